// Round 27
// baseline (99.413 us; speedup 1.0000x reference)
//
#include <hip/hip_runtime.h>

#define D 128
#define NPB 128             // nodes per coarse bucket
#define NBMAX 1024          // max buckets (N <= 131072)
#define TILE_E 8192         // edges per bin tile (1024 threads x 8 edges)
#define CAP2 2560           // slots per bucket slab (mean 2048, +11 sigma)
#define CAP2H 3584          // per-half LDS capacity: 2560 + 64*15 = 3520 <= 3584
#define NMSTR 136           // nmT LDS row stride in bf16 (272B, 16B-aligned)
#define BSTR2 72            // GEMM B staging stride in bf16 (144B, 16B-aligned)
#define CONV_BLOCKS 128     // 1024-thread blocks doing the convert sweep

typedef short bf16x8 __attribute__((ext_vector_type(8)));
typedef float f32x4  __attribute__((ext_vector_type(4)));
typedef float f32x2  __attribute__((ext_vector_type(2)));

__device__ inline unsigned pack_bf2(float a, float b) {
    unsigned ua = __builtin_bit_cast(unsigned, a);
    unsigned ub = __builtin_bit_cast(unsigned, b);
    ua = (ua + 0x7FFFu + ((ua >> 16) & 1u)) >> 16;   // RNE
    ub = (ub + 0x7FFFu + ((ub >> 16) & 1u)) >> 16;
    return ua | (ub << 16);
}

// ------- Pass 0: zero bucket_cnt on the COMPUTE queue -------
__global__ __launch_bounds__(1024) void zero_kernel(unsigned* __restrict__ p, int n)
{
    int i = threadIdx.x;
    if (i < n) p[i] = 0u;
}

// ------- Pass 1 (fused, 1024-thread blocks): bin tiles first (latency-bound
//         critical path), then convert sweep (also zeroes dummy row xq[Nn]).
__global__ __launch_bounds__(1024) void prep_kernel(
    const float* __restrict__ x, unsigned* __restrict__ xq, int total8,
    const float* __restrict__ Wself, const float* __restrict__ Wnei,
    unsigned short* __restrict__ wb, int w8,
    const int* __restrict__ src, const int* __restrict__ dst,
    unsigned* __restrict__ bucket_cnt, unsigned* __restrict__ edges,
    int E, int NB, int binBlocks)
{
    __shared__ unsigned lcnt[NBMAX];
    __shared__ unsigned lbase[NBMAX];
    const int tid = threadIdx.x;

    if (blockIdx.x >= binBlocks) {
        // ---- convert sweep ----
        const int cb = blockIdx.x - binBlocks;
        const int stride = CONV_BLOCKS * 1024;
        const int tot = total8 + 16 + 2 * w8;   // +16: zero dummy row xq[Nn]
        for (int i = cb * 1024 + tid; i < tot; i += stride) {
            if (i < total8) {
                const float4* p = reinterpret_cast<const float4*>(x + (size_t)i * 8);
                float4 a = p[0], b = p[1];
                int q0 = __builtin_amdgcn_cvt_pk_fp8_f32(a.x, a.y, 0, false);
                q0     = __builtin_amdgcn_cvt_pk_fp8_f32(a.z, a.w, q0, true);
                int q1 = __builtin_amdgcn_cvt_pk_fp8_f32(b.x, b.y, 0, false);
                q1     = __builtin_amdgcn_cvt_pk_fp8_f32(b.z, b.w, q1, true);
                reinterpret_cast<uint2*>(xq)[i] = make_uint2((unsigned)q0, (unsigned)q1);
            } else if (i < total8 + 16) {
                reinterpret_cast<uint2*>(xq)[i] = make_uint2(0u, 0u);
            } else {
                const float* srcp;
                unsigned short* dstp;
                int j;
                int ib = i - 16;
                if (ib < total8 + w8) { srcp = Wself; dstp = wb;          j = ib - total8; }
                else                  { srcp = Wnei;  dstp = wb + w8 * 8; j = ib - total8 - w8; }
                const float4* p = reinterpret_cast<const float4*>(srcp + (size_t)j * 8);
                float4 a = p[0], b = p[1];
                reinterpret_cast<uint4*>(dstp)[j] =
                    make_uint4(pack_bf2(a.x, a.y), pack_bf2(a.z, a.w),
                               pack_bf2(b.x, b.y), pack_bf2(b.z, b.w));
            }
        }
        return;
    }

    // ---- bin tile: 8 edges per thread, register-resident ----
    const int e0 = blockIdx.x * TILE_E + tid * 8;
    int d8[8], s8[8];
    if (e0 + 8 <= E) {
        int4 a = *reinterpret_cast<const int4*>(dst + e0);
        int4 b = *reinterpret_cast<const int4*>(dst + e0 + 4);
        d8[0] = a.x; d8[1] = a.y; d8[2] = a.z; d8[3] = a.w;
        d8[4] = b.x; d8[5] = b.y; d8[6] = b.z; d8[7] = b.w;
        int4 c = *reinterpret_cast<const int4*>(src + e0);
        int4 e = *reinterpret_cast<const int4*>(src + e0 + 4);
        s8[0] = c.x; s8[1] = c.y; s8[2] = c.z; s8[3] = c.w;
        s8[4] = e.x; s8[5] = e.y; s8[6] = e.z; s8[7] = e.w;
    } else {
#pragma unroll
        for (int k = 0; k < 8; k++) {
            bool v = (e0 + k) < E;
            d8[k] = v ? dst[e0 + k] : -1;
            s8[k] = v ? src[e0 + k] : 0;
        }
    }

    for (int i = tid; i < NB; i += 1024) lcnt[i] = 0;
    __syncthreads();
#pragma unroll
    for (int k = 0; k < 8; k++)
        if (d8[k] >= 0) atomicAdd(&lcnt[((unsigned)d8[k]) >> 7], 1u);
    __syncthreads();
    for (int i = tid; i < NB; i += 1024) {
        unsigned c = lcnt[i];
        lbase[i] = c ? ((unsigned)i * CAP2 + atomicAdd(&bucket_cnt[i], c)) : 0u;
        lcnt[i] = 0;
    }
    __syncthreads();
#pragma unroll
    for (int k = 0; k < 8; k++) {
        if (d8[k] >= 0) {
            unsigned d_ = (unsigned)d8[k];
            unsigned b  = d_ >> 7;
            unsigned r  = atomicAdd(&lcnt[b], 1u);
            unsigned slot = lbase[b] + r;
            if (slot < (b + 1u) * CAP2)   // overflow guard (statistically unreachable)
                edges[slot] = ((d_ & 127u) << 20) | (unsigned)s8[k];
        }
    }
}

// -------- Pass 2 (FUSED gather + GEMM): one 512-thread block per 64 nodes.
// Phase A: per-half fine CSR in LDS + fp8 gather-mean into LDS nmT + tdeg.
// Phase B: MFMA GEMM; A x-half loaded DIRECTLY from global x (fp32->bf16 in
//          regs, L2-hot), A nm-half from nmT (LDS), B staged in the union.
// LDS ~36.9KB -> 4 blocks/CU = 32 waves full residency for the gather phase.
__global__ __launch_bounds__(512, 8) void gg_kernel(
    const unsigned char* __restrict__ xq,
    const float* __restrict__ x,
    const unsigned short* __restrict__ wb,
    const float* __restrict__ bself, const float* __restrict__ bnei,
    const unsigned* __restrict__ bucket_cnt,
    const unsigned* __restrict__ edges,
    float* __restrict__ out, int Nn)
{
    __shared__ unsigned short nmT[64 * NMSTR];     // 17,408 B
    __shared__ unsigned short uni[9216];           // 18,432 B (lds_src | Bs)
    __shared__ unsigned shc[64];
    __shared__ unsigned offs[64 + 1];
    __shared__ unsigned cursors[64];
    __shared__ unsigned tdeg[64];

    unsigned* lds_src  = reinterpret_cast<unsigned*>(uni);  // CAP2H u32 = 14,336B
    unsigned short* Bs = uni;                               // 128*BSTR2 = 18,432B

    const int b   = blockIdx.x >> 1;       // bucket
    const int hb  = blockIdx.x & 1;        // 64-node half owned by this block
    const int tid = threadIdx.x;
    const int n0  = b * NPB + hb * 64;     // first node of this half
    const unsigned start = (unsigned)b * CAP2;
    unsigned cnt = bucket_cnt[b];
    if (cnt > CAP2) cnt = CAP2;            // matches bin's overflow guard

    // ================= Phase A: CSR build + gather-mean -> nmT =================
    if (tid < 64) shc[tid] = 0;
    __syncthreads();
    for (unsigned i = tid; i < cnt; i += 512) {
        unsigned node = edges[start + i] >> 20;
        if ((int)(node >> 6) == hb) atomicAdd(&shc[node & 63u], 1u);
    }
    __syncthreads();
    unsigned myc = (tid < 64) ? shc[tid] : 0u;
    unsigned pc  = (myc + 15u) & ~15u;     // padded count (multiple of 16)
    if (tid < 64) shc[tid] = pc;
    __syncthreads();
    for (int off = 1; off < 64; off <<= 1) {
        unsigned v = (tid < 64 && tid >= off) ? shc[tid - off] : 0u;
        __syncthreads();
        if (tid < 64) shc[tid] += v;
        __syncthreads();
    }
    if (tid < 64) {
        unsigned ex = shc[tid] - pc;
        offs[tid] = ex;
        cursors[tid] = ex;
        tdeg[tid] = myc;
    }
    if (tid == 63) offs[64] = shc[63];
    __syncthreads();
    for (unsigned i = tid; i < cnt; i += 512) {
        unsigned e = edges[start + i];
        unsigned node = e >> 20;
        if ((int)(node >> 6) == hb) {
            unsigned slot = atomicAdd(&cursors[node & 63u], 1u);
            lds_src[slot] = e & 0xFFFFFu;
        }
    }
    if (tid < 64) {
        unsigned lo = offs[tid] + myc;
        unsigned hi = offs[tid] + pc;
        for (unsigned j = lo; j < hi; j++) lds_src[j] = (unsigned)Nn;
    }
    __syncthreads();

    {
        const int w      = tid >> 6;        // wave 0..7
        const int lane   = tid & 63;
        const int half   = lane >> 5;
        const int lane32 = lane & 31;
        const int q2     = lane32 >> 4;     // row-within-pair
        const int sub    = lane32 & 15;     // 8B chunk within 128B fp8 row

#define ACCQ(u) do { \
    acc[0] += __builtin_amdgcn_cvt_pk_f32_fp8((int)(u).x, false); \
    acc[1] += __builtin_amdgcn_cvt_pk_f32_fp8((int)(u).x, true);  \
    acc[2] += __builtin_amdgcn_cvt_pk_f32_fp8((int)(u).y, false); \
    acc[3] += __builtin_amdgcn_cvt_pk_f32_fp8((int)(u).y, true);  } while (0)

        for (int jj = 0; jj < 4; jj++) {
            const int ln = w * 8 + jj * 2 + half;   // local node 0..63
            f32x2 acc[4] = {f32x2{0.f, 0.f}, f32x2{0.f, 0.f},
                            f32x2{0.f, 0.f}, f32x2{0.f, 0.f}};
            const unsigned o = offs[ln];
            const unsigned c = offs[ln + 1] - o;    // padded, multiple of 16
            const unsigned tc = tdeg[ln];
            for (unsigned i = 0; i < c; i += 16) {
                uint2 v[8];
#pragma unroll
                for (int l = 0; l < 8; l++)
                    v[l] = *reinterpret_cast<const uint2*>(
                        xq + (size_t)lds_src[o + i + 2 * l + q2] * D + sub * 8);
#pragma unroll
                for (int l = 0; l < 8; l++) ACCQ(v[l]);
            }
#pragma unroll
            for (int q = 0; q < 4; q++) {
                acc[q].x += __shfl_xor(acc[q].x, 16);
                acc[q].y += __shfl_xor(acc[q].y, 16);
            }
            if (lane32 < 16) {
                uint4 wv = make_uint4(0u, 0u, 0u, 0u);
                if (tc) {
                    float inv = 1.0f / (float)tc;
                    wv = make_uint4(pack_bf2(acc[0].x * inv, acc[0].y * inv),
                                    pack_bf2(acc[1].x * inv, acc[1].y * inv),
                                    pack_bf2(acc[2].x * inv, acc[2].y * inv),
                                    pack_bf2(acc[3].x * inv, acc[3].y * inv));
                }
                *reinterpret_cast<uint4*>(&nmT[ln * NMSTR + sub * 8]) = wv;
            }
        }
#undef ACCQ
    }
    __syncthreads();   // nmT complete; lds_src dead -> union becomes Bs

    // ================= Phase B: GEMM 64 x 128 over K=256 =================
    const int lane = tid & 63;
    const int w    = tid >> 6;
    const int wm   = w >> 2;        // 0..1 -> row block of 32
    const int wn   = w & 3;         // 0..3 -> col block of 32

    f32x4 acc2[2][2];
#pragma unroll
    for (int i = 0; i < 2; i++)
#pragma unroll
        for (int j = 0; j < 2; j++) acc2[i][j] = (f32x4)(0.f);

    const int brow = tid >> 2;      // 0..127 (B staging: 4 threads/row)
    const int bq   = tid & 3;       // 16-elem quarter

    for (int ks = 0; ks < 4; ks++) {
        // ---- stage Bs: 128 rows x 64 k ----
        {
            const int koff = (ks & 1) * 64 + bq * 16;
            const unsigned short* srcB = (ks < 2) ? wb : wb + D * D;
            const uint4* p = reinterpret_cast<const uint4*>(
                srcB + (size_t)brow * D + koff);
            uint4* dstp = reinterpret_cast<uint4*>(&Bs[brow * BSTR2 + bq * 16]);
            dstp[0] = p[0]; dstp[1] = p[1];
        }
        __syncthreads();

        const int hi8 = (lane >> 4) * 8;
#pragma unroll
        for (int ksub = 0; ksub < 2; ksub++) {
            bf16x8 af[2], bf[2];
#pragma unroll
            for (int mr = 0; mr < 2; mr++) {
                const int row = wm * 32 + mr * 16 + (lane & 15);
                if (ks < 2) {
                    const int n = n0 + row;
                    uint4 wv = make_uint4(0u, 0u, 0u, 0u);
                    if (n < Nn) {
                        const float4* p = reinterpret_cast<const float4*>(
                            x + (size_t)n * D + ks * 64 + ksub * 32 + hi8);
                        float4 f0 = p[0], f1 = p[1];
                        wv = make_uint4(pack_bf2(f0.x, f0.y), pack_bf2(f0.z, f0.w),
                                        pack_bf2(f1.x, f1.y), pack_bf2(f1.z, f1.w));
                    }
                    af[mr] = __builtin_bit_cast(bf16x8, wv);
                } else {
                    af[mr] = *reinterpret_cast<const bf16x8*>(
                        &nmT[row * NMSTR + (ks - 2) * 64 + ksub * 32 + hi8]);
                }
            }
#pragma unroll
            for (int nr = 0; nr < 2; nr++)
                bf[nr] = *reinterpret_cast<const bf16x8*>(
                    &Bs[(wn * 32 + nr * 16 + (lane & 15)) * BSTR2 + ksub * 32 + hi8]);
#pragma unroll
            for (int mr = 0; mr < 2; mr++)
#pragma unroll
                for (int nr = 0; nr < 2; nr++)
                    acc2[mr][nr] = __builtin_amdgcn_mfma_f32_16x16x32_bf16(
                        af[mr], bf[nr], acc2[mr][nr], 0, 0, 0);
        }
        __syncthreads();
    }

    float bsv[2], bnv[2];
#pragma unroll
    for (int nr = 0; nr < 2; nr++) {
        int d_ = wn * 32 + nr * 16 + (lane & 15);
        bsv[nr] = bself[d_];
        bnv[nr] = bnei[d_];
    }
#pragma unroll
    for (int mr = 0; mr < 2; mr++) {
#pragma unroll
        for (int r = 0; r < 4; r++) {
            int ln = wm * 32 + mr * 16 + (lane >> 4) * 4 + r;
            int node = n0 + ln;
            if (node < Nn) {
                float hd = (tdeg[ln] > 0u) ? 1.f : 0.f;
                float* op = out + (size_t)node * D + wn * 32 + (lane & 15);
#pragma unroll
                for (int nr = 0; nr < 2; nr++) {
                    float v = acc2[mr][nr][r] + bsv[nr] + hd * bnv[nr];
                    op[nr * 16] = fmaxf(v, 0.f);
                }
            }
        }
    }
}

extern "C" void kernel_launch(void* const* d_in, const int* in_sizes, int n_in,
                              void* d_out, int out_size, void* d_ws, size_t ws_size,
                              hipStream_t stream)
{
    const float* x     = (const float*)d_in[0];
    const int*   src   = (const int*)  d_in[1];
    const int*   dst   = (const int*)  d_in[2];
    const float* Wself = (const float*)d_in[3];
    const float* bself = (const float*)d_in[4];
    const float* Wnei  = (const float*)d_in[5];
    const float* bnei  = (const float*)d_in[6];
    float* out = (float*)d_out;

    const int Nn = in_sizes[0] / D;
    const int E  = in_sizes[1];
    const int NB = (Nn + NPB - 1) / NPB;

    // Workspace (u32 units): ~21 MB total
    unsigned* bucket_cnt = (unsigned*)d_ws;                          // NBMAX
    unsigned* edges      = bucket_cnt + NBMAX;                       // NB*CAP2
    unsigned short* wb   = (unsigned short*)(edges + (size_t)NB * CAP2); // 2*D*D bf16
    unsigned* xq         = (unsigned*)(wb + 2 * D * D);              // (N+1)*D fp8

    zero_kernel<<<1, 1024, 0, stream>>>(bucket_cnt, NBMAX);

    int total8 = (Nn * D) / 8;
    int w8 = (D * D) / 8;
    int binBlocks = (E + TILE_E - 1) / TILE_E;
    prep_kernel<<<binBlocks + CONV_BLOCKS, 1024, 0, stream>>>(
        x, xq, total8, Wself, Wnei, wb, w8,
        src, dst, bucket_cnt, edges, E, NB, binBlocks);

    gg_kernel<<<NB * 2, 512, 0, stream>>>((const unsigned char*)xq, x, wb,
                                          bself, bnei, bucket_cnt, edges,
                                          out, Nn);
}

// Round 28
// 83.927 us; speedup vs baseline: 1.1845x; 1.1845x over previous
//
#include <hip/hip_runtime.h>

#define D 128
#define NPB 128             // nodes per coarse bucket
#define NBMAX 1024          // max buckets (N <= 131072)
#define TILE_E 8192         // edges per bin tile (1024 threads x 8 edges)
#define CAP2 2560           // slots per bucket slab (mean 2048, +11 sigma)
#define CAP2H 3584          // per-half LDS capacity: 2560 + 64*15 = 3520 <= 3584
#define NMSTR 136           // nmT LDS row stride in bf16 (272B, 16B-aligned)
#define BSTR 40             // GEMM staging stride in bf16 (80B, 16B-aligned, BK=32)
#define CONV_BLOCKS 128     // 1024-thread blocks doing the convert sweep

typedef short bf16x8 __attribute__((ext_vector_type(8)));
typedef float f32x4  __attribute__((ext_vector_type(4)));
typedef float f32x2  __attribute__((ext_vector_type(2)));

__device__ inline unsigned pack_bf2(float a, float b) {
    unsigned ua = __builtin_bit_cast(unsigned, a);
    unsigned ub = __builtin_bit_cast(unsigned, b);
    ua = (ua + 0x7FFFu + ((ua >> 16) & 1u)) >> 16;   // RNE
    ub = (ub + 0x7FFFu + ((ub >> 16) & 1u)) >> 16;
    return ua | (ub << 16);
}

// ------- Pass 0: zero bucket_cnt on the COMPUTE queue -------
__global__ __launch_bounds__(1024) void zero_kernel(unsigned* __restrict__ p, int n)
{
    int i = threadIdx.x;
    if (i < n) p[i] = 0u;
}

// ------- Pass 1 (fused, 1024-thread blocks): bin tiles first (latency-bound
//         critical path), then convert sweep (also zeroes dummy row xq[Nn]).
__global__ __launch_bounds__(1024) void prep_kernel(
    const float* __restrict__ x, unsigned* __restrict__ xq, int total8,
    const float* __restrict__ Wself, const float* __restrict__ Wnei,
    unsigned short* __restrict__ wb, int w8,
    const int* __restrict__ src, const int* __restrict__ dst,
    unsigned* __restrict__ bucket_cnt, unsigned* __restrict__ edges,
    int E, int NB, int binBlocks)
{
    __shared__ unsigned lcnt[NBMAX];
    __shared__ unsigned lbase[NBMAX];
    const int tid = threadIdx.x;

    if (blockIdx.x >= binBlocks) {
        // ---- convert sweep ----
        const int cb = blockIdx.x - binBlocks;
        const int stride = CONV_BLOCKS * 1024;
        const int tot = total8 + 16 + 2 * w8;   // +16: zero dummy row xq[Nn]
        for (int i = cb * 1024 + tid; i < tot; i += stride) {
            if (i < total8) {
                const float4* p = reinterpret_cast<const float4*>(x + (size_t)i * 8);
                float4 a = p[0], b = p[1];
                int q0 = __builtin_amdgcn_cvt_pk_fp8_f32(a.x, a.y, 0, false);
                q0     = __builtin_amdgcn_cvt_pk_fp8_f32(a.z, a.w, q0, true);
                int q1 = __builtin_amdgcn_cvt_pk_fp8_f32(b.x, b.y, 0, false);
                q1     = __builtin_amdgcn_cvt_pk_fp8_f32(b.z, b.w, q1, true);
                reinterpret_cast<uint2*>(xq)[i] = make_uint2((unsigned)q0, (unsigned)q1);
            } else if (i < total8 + 16) {
                reinterpret_cast<uint2*>(xq)[i] = make_uint2(0u, 0u);
            } else {
                const float* srcp;
                unsigned short* dstp;
                int j;
                int ib = i - 16;
                if (ib < total8 + w8) { srcp = Wself; dstp = wb;          j = ib - total8; }
                else                  { srcp = Wnei;  dstp = wb + w8 * 8; j = ib - total8 - w8; }
                const float4* p = reinterpret_cast<const float4*>(srcp + (size_t)j * 8);
                float4 a = p[0], b = p[1];
                reinterpret_cast<uint4*>(dstp)[j] =
                    make_uint4(pack_bf2(a.x, a.y), pack_bf2(a.z, a.w),
                               pack_bf2(b.x, b.y), pack_bf2(b.z, b.w));
            }
        }
        return;
    }

    // ---- bin tile: 8 edges per thread, register-resident ----
    const int e0 = blockIdx.x * TILE_E + tid * 8;
    int d8[8], s8[8];
    if (e0 + 8 <= E) {
        int4 a = *reinterpret_cast<const int4*>(dst + e0);
        int4 b = *reinterpret_cast<const int4*>(dst + e0 + 4);
        d8[0] = a.x; d8[1] = a.y; d8[2] = a.z; d8[3] = a.w;
        d8[4] = b.x; d8[5] = b.y; d8[6] = b.z; d8[7] = b.w;
        int4 c = *reinterpret_cast<const int4*>(src + e0);
        int4 e = *reinterpret_cast<const int4*>(src + e0 + 4);
        s8[0] = c.x; s8[1] = c.y; s8[2] = c.z; s8[3] = c.w;
        s8[4] = e.x; s8[5] = e.y; s8[6] = e.z; s8[7] = e.w;
    } else {
#pragma unroll
        for (int k = 0; k < 8; k++) {
            bool v = (e0 + k) < E;
            d8[k] = v ? dst[e0 + k] : -1;
            s8[k] = v ? src[e0 + k] : 0;
        }
    }

    for (int i = tid; i < NB; i += 1024) lcnt[i] = 0;
    __syncthreads();
#pragma unroll
    for (int k = 0; k < 8; k++)
        if (d8[k] >= 0) atomicAdd(&lcnt[((unsigned)d8[k]) >> 7], 1u);
    __syncthreads();
    for (int i = tid; i < NB; i += 1024) {
        unsigned c = lcnt[i];
        lbase[i] = c ? ((unsigned)i * CAP2 + atomicAdd(&bucket_cnt[i], c)) : 0u;
        lcnt[i] = 0;
    }
    __syncthreads();
#pragma unroll
    for (int k = 0; k < 8; k++) {
        if (d8[k] >= 0) {
            unsigned d_ = (unsigned)d8[k];
            unsigned b  = d_ >> 7;
            unsigned r  = atomicAdd(&lcnt[b], 1u);
            unsigned slot = lbase[b] + r;
            if (slot < (b + 1u) * CAP2)   // overflow guard (statistically unreachable)
                edges[slot] = ((d_ & 127u) << 20) | (unsigned)s8[k];
        }
    }
}

// -------- Pass 2 (FUSED gather + GEMM): one 512-thread block per 64 nodes.
// Phase A: per-half fine CSR in LDS + fp8 gather-mean into LDS nmT + tdeg.
// Phase B: MFMA GEMM, BK=32 staging (As_x 5.1KB + Bs 10.2KB union with
//          lds_src). Total LDS ~33.8KB -> 4 blocks/CU = 32 waves residency.
__global__ __launch_bounds__(512, 8) void gg_kernel(
    const unsigned char* __restrict__ xq,
    const float* __restrict__ x,
    const unsigned short* __restrict__ wb,
    const float* __restrict__ bself, const float* __restrict__ bnei,
    const unsigned* __restrict__ bucket_cnt,
    const unsigned* __restrict__ edges,
    float* __restrict__ out, int Nn)
{
    __shared__ unsigned short nmT[64 * NMSTR];     // 17,408 B
    __shared__ unsigned short uni[7680];           // 15,360 B (lds_src | As_x+Bs)
    __shared__ unsigned shc[64];
    __shared__ unsigned offs[64 + 1];
    __shared__ unsigned cursors[64];
    __shared__ unsigned tdeg[64];

    unsigned* lds_src    = reinterpret_cast<unsigned*>(uni); // CAP2H u32 = 14,336B
    unsigned short* As_x = uni;                    // 64*BSTR  = 2,560 ushorts
    unsigned short* Bs   = uni + 64 * BSTR;        // 128*BSTR = 5,120 ushorts

    const int b   = blockIdx.x >> 1;       // bucket
    const int hb  = blockIdx.x & 1;        // 64-node half owned by this block
    const int tid = threadIdx.x;
    const int n0  = b * NPB + hb * 64;     // first node of this half
    const unsigned start = (unsigned)b * CAP2;
    unsigned cnt = bucket_cnt[b];
    if (cnt > CAP2) cnt = CAP2;            // matches bin's overflow guard

    // ================= Phase A: CSR build + gather-mean -> nmT =================
    if (tid < 64) shc[tid] = 0;
    __syncthreads();
    for (unsigned i = tid; i < cnt; i += 512) {
        unsigned node = edges[start + i] >> 20;
        if ((int)(node >> 6) == hb) atomicAdd(&shc[node & 63u], 1u);
    }
    __syncthreads();
    unsigned myc = (tid < 64) ? shc[tid] : 0u;
    unsigned pc  = (myc + 15u) & ~15u;     // padded count (multiple of 16)
    if (tid < 64) shc[tid] = pc;
    __syncthreads();
    for (int off = 1; off < 64; off <<= 1) {
        unsigned v = (tid < 64 && tid >= off) ? shc[tid - off] : 0u;
        __syncthreads();
        if (tid < 64) shc[tid] += v;
        __syncthreads();
    }
    if (tid < 64) {
        unsigned ex = shc[tid] - pc;
        offs[tid] = ex;
        cursors[tid] = ex;
        tdeg[tid] = myc;
    }
    if (tid == 63) offs[64] = shc[63];
    __syncthreads();
    for (unsigned i = tid; i < cnt; i += 512) {
        unsigned e = edges[start + i];
        unsigned node = e >> 20;
        if ((int)(node >> 6) == hb) {
            unsigned slot = atomicAdd(&cursors[node & 63u], 1u);
            lds_src[slot] = e & 0xFFFFFu;
        }
    }
    if (tid < 64) {
        unsigned lo = offs[tid] + myc;
        unsigned hi = offs[tid] + pc;
        for (unsigned j = lo; j < hi; j++) lds_src[j] = (unsigned)Nn;
    }
    __syncthreads();

    {
        const int w      = tid >> 6;        // wave 0..7
        const int lane   = tid & 63;
        const int half   = lane >> 5;
        const int lane32 = lane & 31;
        const int q2     = lane32 >> 4;     // row-within-pair
        const int sub    = lane32 & 15;     // 8B chunk within 128B fp8 row

#define ACCQ(u) do { \
    acc[0] += __builtin_amdgcn_cvt_pk_f32_fp8((int)(u).x, false); \
    acc[1] += __builtin_amdgcn_cvt_pk_f32_fp8((int)(u).x, true);  \
    acc[2] += __builtin_amdgcn_cvt_pk_f32_fp8((int)(u).y, false); \
    acc[3] += __builtin_amdgcn_cvt_pk_f32_fp8((int)(u).y, true);  } while (0)

        for (int jj = 0; jj < 4; jj++) {
            const int ln = w * 8 + jj * 2 + half;   // local node 0..63
            f32x2 acc[4] = {f32x2{0.f, 0.f}, f32x2{0.f, 0.f},
                            f32x2{0.f, 0.f}, f32x2{0.f, 0.f}};
            const unsigned o = offs[ln];
            const unsigned c = offs[ln + 1] - o;    // padded, multiple of 16
            const unsigned tc = tdeg[ln];
            for (unsigned i = 0; i < c; i += 16) {
                uint2 v[8];
#pragma unroll
                for (int l = 0; l < 8; l++)
                    v[l] = *reinterpret_cast<const uint2*>(
                        xq + (size_t)lds_src[o + i + 2 * l + q2] * D + sub * 8);
#pragma unroll
                for (int l = 0; l < 8; l++) ACCQ(v[l]);
            }
#pragma unroll
            for (int q = 0; q < 4; q++) {
                acc[q].x += __shfl_xor(acc[q].x, 16);
                acc[q].y += __shfl_xor(acc[q].y, 16);
            }
            if (lane32 < 16) {
                uint4 wv = make_uint4(0u, 0u, 0u, 0u);
                if (tc) {
                    float inv = 1.0f / (float)tc;
                    wv = make_uint4(pack_bf2(acc[0].x * inv, acc[0].y * inv),
                                    pack_bf2(acc[1].x * inv, acc[1].y * inv),
                                    pack_bf2(acc[2].x * inv, acc[2].y * inv),
                                    pack_bf2(acc[3].x * inv, acc[3].y * inv));
                }
                *reinterpret_cast<uint4*>(&nmT[ln * NMSTR + sub * 8]) = wv;
            }
        }
#undef ACCQ
    }
    __syncthreads();   // nmT complete; lds_src dead -> union becomes As_x/Bs

    // ================= Phase B: GEMM 64 x 128 over K=256, BK=32 =================
    const int lane = tid & 63;
    const int w    = tid >> 6;
    const int wm   = w >> 2;        // 0..1 -> row block of 32
    const int wn   = w & 3;         // 0..3 -> col block of 32

    f32x4 acc2[2][2];
#pragma unroll
    for (int i = 0; i < 2; i++)
#pragma unroll
        for (int j = 0; j < 2; j++) acc2[i][j] = (f32x4)(0.f);

    const int arow = tid >> 3;      // 0..63 (A staging: 8 threads/row)
    const int aoct = tid & 7;       // 4-elem chunk within 32-k
    const int brow = tid >> 2;      // 0..127 (B staging: 4 threads/row)
    const int bq   = tid & 3;       // 8-elem chunk within 32-k

    for (int ks = 0; ks < 8; ks++) {
        // ---- stage As_x from x (fp32->bf16) only for ks<4 ----
        if (ks < 4) {
            const int n = n0 + arow;
            uint2 w0 = make_uint2(0u, 0u);
            if (n < Nn) {
                const float4 f = *reinterpret_cast<const float4*>(
                    x + (size_t)n * D + ks * 32 + aoct * 4);
                w0 = make_uint2(pack_bf2(f.x, f.y), pack_bf2(f.z, f.w));
            }
            *reinterpret_cast<uint2*>(&As_x[arow * BSTR + aoct * 4]) = w0;
        }
        // ---- stage Bs: 128 rows x 32 k ----
        {
            const int koff = (ks & 3) * 32 + bq * 8;
            const unsigned short* srcB = (ks < 4) ? wb : wb + D * D;
            const uint4 p = *reinterpret_cast<const uint4*>(
                srcB + (size_t)brow * D + koff);
            *reinterpret_cast<uint4*>(&Bs[brow * BSTR + bq * 8]) = p;
        }
        __syncthreads();

        const int hi8 = (lane >> 4) * 8;
        bf16x8 af[2], bf[2];
#pragma unroll
        for (int mr = 0; mr < 2; mr++) {
            const int row = wm * 32 + mr * 16 + (lane & 15);
            af[mr] = (ks < 4)
                ? *reinterpret_cast<const bf16x8*>(&As_x[row * BSTR + hi8])
                : *reinterpret_cast<const bf16x8*>(
                      &nmT[row * NMSTR + (ks - 4) * 32 + hi8]);
        }
#pragma unroll
        for (int nr = 0; nr < 2; nr++)
            bf[nr] = *reinterpret_cast<const bf16x8*>(
                &Bs[(wn * 32 + nr * 16 + (lane & 15)) * BSTR + hi8]);
#pragma unroll
        for (int mr = 0; mr < 2; mr++)
#pragma unroll
            for (int nr = 0; nr < 2; nr++)
                acc2[mr][nr] = __builtin_amdgcn_mfma_f32_16x16x32_bf16(
                    af[mr], bf[nr], acc2[mr][nr], 0, 0, 0);
        __syncthreads();
    }

    float bsv[2], bnv[2];
#pragma unroll
    for (int nr = 0; nr < 2; nr++) {
        int d_ = wn * 32 + nr * 16 + (lane & 15);
        bsv[nr] = bself[d_];
        bnv[nr] = bnei[d_];
    }
#pragma unroll
    for (int mr = 0; mr < 2; mr++) {
#pragma unroll
        for (int r = 0; r < 4; r++) {
            int ln = wm * 32 + mr * 16 + (lane >> 4) * 4 + r;
            int node = n0 + ln;
            if (node < Nn) {
                float hd = (tdeg[ln] > 0u) ? 1.f : 0.f;
                float* op = out + (size_t)node * D + wn * 32 + (lane & 15);
#pragma unroll
                for (int nr = 0; nr < 2; nr++) {
                    float v = acc2[mr][nr][r] + bsv[nr] + hd * bnv[nr];
                    op[nr * 16] = fmaxf(v, 0.f);
                }
            }
        }
    }
}

extern "C" void kernel_launch(void* const* d_in, const int* in_sizes, int n_in,
                              void* d_out, int out_size, void* d_ws, size_t ws_size,
                              hipStream_t stream)
{
    const float* x     = (const float*)d_in[0];
    const int*   src   = (const int*)  d_in[1];
    const int*   dst   = (const int*)  d_in[2];
    const float* Wself = (const float*)d_in[3];
    const float* bself = (const float*)d_in[4];
    const float* Wnei  = (const float*)d_in[5];
    const float* bnei  = (const float*)d_in[6];
    float* out = (float*)d_out;

    const int Nn = in_sizes[0] / D;
    const int E  = in_sizes[1];
    const int NB = (Nn + NPB - 1) / NPB;

    // Workspace (u32 units): ~21 MB total
    unsigned* bucket_cnt = (unsigned*)d_ws;                          // NBMAX
    unsigned* edges      = bucket_cnt + NBMAX;                       // NB*CAP2
    unsigned short* wb   = (unsigned short*)(edges + (size_t)NB * CAP2); // 2*D*D bf16
    unsigned* xq         = (unsigned*)(wb + 2 * D * D);              // (N+1)*D fp8

    zero_kernel<<<1, 1024, 0, stream>>>(bucket_cnt, NBMAX);

    int total8 = (Nn * D) / 8;
    int w8 = (D * D) / 8;
    int binBlocks = (E + TILE_E - 1) / TILE_E;
    prep_kernel<<<binBlocks + CONV_BLOCKS, 1024, 0, stream>>>(
        x, xq, total8, Wself, Wnei, wb, w8,
        src, dst, bucket_cnt, edges, E, NB, binBlocks);

    gg_kernel<<<NB * 2, 512, 0, stream>>>((const unsigned char*)xq, x, wb,
                                          bself, bnei, bucket_cnt, edges,
                                          out, Nn);
}